// Round 16
// baseline (224.116 us; speedup 1.0000x reference)
//
#include <hip/hip_runtime.h>
#include <hip/hip_bf16.h>
#include <stdint.h>

typedef __bf16 bf16x8 __attribute__((ext_vector_type(8)));
typedef short short8 __attribute__((ext_vector_type(8)));
typedef float f32x4 __attribute__((ext_vector_type(4)));

#define LOG2E 1.44269504088896340736f

__device__ inline void gload_lds16(const void* g, void* l) {
  __builtin_amdgcn_global_load_lds((const __attribute__((address_space(1))) void*)g,
                                   (__attribute__((address_space(3))) void*)l, 16, 0, 0);
}

__device__ inline unsigned short bf16_bits(float f) {
  return __builtin_bit_cast(unsigned short, __float2bfloat16(f));
}

// raw v_exp_f32 (exp2f is a multi-instruction OCML call; scores are bounded)
__device__ inline float fast_exp2(float x) {
  return __builtin_amdgcn_exp2f(x);
}

// pack two f32 -> one u32 of 2 bf16 (low = first arg)
__device__ inline uint32_t cvtpk_bf16(float lo, float hi) {
  uint32_t d;
  asm("v_cvt_pk_bf16_f32 %0, %1, %2" : "=v"(d) : "v"(lo), "v"(hi));
  return d;
}
// gfx950 cross-lane row swaps
__device__ inline void plswap32(uint32_t& a, uint32_t& b) {
  asm("v_permlane32_swap_b32 %0, %1" : "+v"(a), "+v"(b));
}
__device__ inline void plswap16(uint32_t& a, uint32_t& b) {
  asm("v_permlane16_swap_b32 %0, %1" : "+v"(a), "+v"(b));
}

// ---------------- prep: LN (blocks 0..8191) + weight cvt (blocks 8192..12287) ----
__global__ __launch_bounds__(256) void prep_kernel(
    const float* __restrict__ x, const float* __restrict__ gamma,
    const float* __restrict__ beta, __hip_bfloat16* __restrict__ xn,
    const float* __restrict__ Wq, const float* __restrict__ Wk,
    const float* __restrict__ Wv, const float* __restrict__ Wo,
    __hip_bfloat16* __restrict__ Wqk, __hip_bfloat16* __restrict__ Wvb,
    __hip_bfloat16* __restrict__ Wob)
{
  const int t = threadIdx.x;
  if (blockIdx.x < 8192) {
    const int row = blockIdx.x;
    const float4 v = reinterpret_cast<const float4*>(x + (size_t)row * 1024)[t];
    float s = v.x + v.y + v.z + v.w;
    float q = v.x*v.x + v.y*v.y + v.z*v.z + v.w*v.w;
    #pragma unroll
    for (int off = 32; off >= 1; off >>= 1) {
      s += __shfl_xor(s, off);
      q += __shfl_xor(q, off);
    }
    __shared__ float ls[4], lq[4];
    const int wave = t >> 6, lane = t & 63;
    if (lane == 0) { ls[wave] = s; lq[wave] = q; }
    __syncthreads();
    s = ls[0] + ls[1] + ls[2] + ls[3];
    q = lq[0] + lq[1] + lq[2] + lq[3];
    const float mean = s * (1.0f/1024.0f);
    const float var  = q * (1.0f/1024.0f) - mean*mean;
    const float rstd = rsqrtf(var + 1e-6f);
    const float4 gm = reinterpret_cast<const float4*>(gamma)[t];
    const float4 bt = reinterpret_cast<const float4*>(beta)[t];
    ushort4 o;
    o.x = bf16_bits((v.x - mean)*rstd*gm.x + bt.x);
    o.y = bf16_bits((v.y - mean)*rstd*gm.y + bt.y);
    o.z = bf16_bits((v.z - mean)*rstd*gm.z + bt.z);
    o.w = bf16_bits((v.w - mean)*rstd*gm.w + bt.w);
    reinterpret_cast<ushort4*>(xn + (size_t)row*1024)[t] = o;
  } else {
    const int cb = blockIdx.x - 8192;        // 0..4095
    const int which = cb >> 10;              // 0..3
    const int i = (cb & 1023) * 256 + t;     // 0..1M-1
    const float* src;
    __hip_bfloat16* dst;
    if (which == 0)      { src = Wq; dst = Wqk; }
    else if (which == 1) { src = Wk; dst = Wqk + 1024*1024; }
    else if (which == 2) { src = Wv; dst = Wvb; }
    else                 { src = Wo; dst = Wob; }
    const float4 v = reinterpret_cast<const float4*>(src)[i];
    ushort4 o;
    o.x = bf16_bits(v.x); o.y = bf16_bits(v.y);
    o.z = bf16_bits(v.z); o.w = bf16_bits(v.w);
    reinterpret_cast<ushort4*>(dst)[i] = o;
  }
}

// ---------------- NT-GEMM 128x128 body (BK=64, XOR-swizzled, R14-proven) --------
// MODE 0 only: C -> Q (scaled, bias bq) / K (bias bk), [b,h,s,d] bf16.
__device__ __forceinline__ void gemm_body128(
    const __hip_bfloat16* __restrict__ A,
    const __hip_bfloat16* __restrict__ B,
    int m0, int n0,
    const float* __restrict__ bq, const float* __restrict__ bk,
    __hip_bfloat16* __restrict__ Qb, __hip_bfloat16* __restrict__ Kb,
    __hip_bfloat16* Al, __hip_bfloat16* Bl)
{
  constexpr int K = 1024;
  const int t = threadIdx.x;
  const int wave = t >> 6, lane = t & 63;
  const int li = lane & 15, g = lane >> 4;
  const int wm = (wave >> 1) * 64, wn = (wave & 1) * 64;

  const int srow = t >> 3;
  const int scb_e = ((((t & 7) * 16) ^ ((srow & 7) << 4)) >> 1);
  const __hip_bfloat16* ga = A + (size_t)(m0 + srow) * K + scb_e;
  const __hip_bfloat16* gb = B + (size_t)(n0 + srow) * K + scb_e;

  const int swz = (li & 7) << 4;
  const int rd0 = (((g*16)      ^ swz) >> 1);
  const int rd1 = (((g*16 + 64) ^ swz) >> 1);

  f32x4 acc[4][4] = {};

  for (int kt = 0; kt < K; kt += 64) {
    #pragma unroll
    for (int i = 0; i < 4; ++i) {
      gload_lds16(ga + (size_t)(i*32)*K + kt, Al + i*2048 + t*8);
      gload_lds16(gb + (size_t)(i*32)*K + kt, Bl + i*2048 + t*8);
    }
    __syncthreads();
    bf16x8 af[4][2], bfr[4][2];
    #pragma unroll
    for (int mi = 0; mi < 4; ++mi) {
      af[mi][0] = *reinterpret_cast<const bf16x8*>(&Al[(wm + mi*16 + li)*64 + rd0]);
      af[mi][1] = *reinterpret_cast<const bf16x8*>(&Al[(wm + mi*16 + li)*64 + rd1]);
    }
    #pragma unroll
    for (int ni = 0; ni < 4; ++ni) {
      bfr[ni][0] = *reinterpret_cast<const bf16x8*>(&Bl[(wn + ni*16 + li)*64 + rd0]);
      bfr[ni][1] = *reinterpret_cast<const bf16x8*>(&Bl[(wn + ni*16 + li)*64 + rd1]);
    }
    __builtin_amdgcn_s_setprio(1);
    #pragma unroll
    for (int mi = 0; mi < 4; ++mi)
      #pragma unroll
      for (int ni = 0; ni < 4; ++ni) {
        acc[mi][ni] = __builtin_amdgcn_mfma_f32_16x16x32_bf16(af[mi][0], bfr[ni][0], acc[mi][ni], 0, 0, 0);
        acc[mi][ni] = __builtin_amdgcn_mfma_f32_16x16x32_bf16(af[mi][1], bfr[ni][1], acc[mi][ni], 0, 0, 0);
      }
    __builtin_amdgcn_s_setprio(0);
    __syncthreads();
  }

  #pragma unroll
  for (int mi = 0; mi < 4; ++mi) {
    #pragma unroll
    for (int ni = 0; ni < 4; ++ni) {
      #pragma unroll
      for (int r = 0; r < 4; ++r) {
        const int grow = m0 + wm + mi*16 + g*4 + r;
        const int gcol = n0 + wn + ni*16 + li;
        float v = acc[mi][ni][r];
        const int b = grow >> 11, ss = grow & 2047;
        if (gcol < 1024) {
          v = (v + bq[gcol]) * (0.125f * LOG2E);   // fold scale*log2(e) into Q
          const int h = gcol >> 6, d = gcol & 63;
          Qb[(((size_t)(b*16 + h))*2048 + ss)*64 + d] = __float2bfloat16(v);
        } else {
          const int c2 = gcol - 1024;
          v = v + bk[c2];
          const int h = c2 >> 6, d = c2 & 63;
          Kb[(((size_t)(b*16 + h))*2048 + ss)*64 + d] = __float2bfloat16(v);
        }
      }
    }
  }
}

// ---------------- NT-GEMM 64x128 thin body (BK=64) ------------------------------
// 4 waves each own full M=64 x N-slice 32 (wn = wave*32). 16 MFMA/wave/K-step.
// MODE 1: C -> Vt bf16 [1024][8192], bias by row. MODE 2: C -> f32 [8192][1024], bias by col.
template<int MODE>
__device__ __forceinline__ void gemm_body_thin(
    const __hip_bfloat16* __restrict__ A,
    const __hip_bfloat16* __restrict__ B,
    int m0, int n0,
    const float* __restrict__ bias,
    void* __restrict__ C,
    __hip_bfloat16* Al, __hip_bfloat16* Bl)
{
  constexpr int K = 1024;
  const int t = threadIdx.x;
  const int wave = t >> 6, lane = t & 63;
  const int li = lane & 15, g = lane >> 4;
  const int wn = wave * 32;

  const int srow = t >> 3;
  const int scb_e = ((((t & 7) * 16) ^ ((srow & 7) << 4)) >> 1);
  const __hip_bfloat16* ga = A + (size_t)(m0 + srow) * K + scb_e;
  const __hip_bfloat16* gb = B + (size_t)(n0 + srow) * K + scb_e;

  const int swz = (li & 7) << 4;
  const int rd0 = (((g*16)      ^ swz) >> 1);
  const int rd1 = (((g*16 + 64) ^ swz) >> 1);

  f32x4 acc[4][2] = {};

  for (int kt = 0; kt < K; kt += 64) {
    #pragma unroll
    for (int i = 0; i < 2; ++i)
      gload_lds16(ga + (size_t)(i*32)*K + kt, Al + i*2048 + t*8);
    #pragma unroll
    for (int i = 0; i < 4; ++i)
      gload_lds16(gb + (size_t)(i*32)*K + kt, Bl + i*2048 + t*8);
    __syncthreads();
    bf16x8 af[4][2], bfr[2][2];
    #pragma unroll
    for (int mi = 0; mi < 4; ++mi) {
      af[mi][0] = *reinterpret_cast<const bf16x8*>(&Al[(mi*16 + li)*64 + rd0]);
      af[mi][1] = *reinterpret_cast<const bf16x8*>(&Al[(mi*16 + li)*64 + rd1]);
    }
    #pragma unroll
    for (int ni = 0; ni < 2; ++ni) {
      bfr[ni][0] = *reinterpret_cast<const bf16x8*>(&Bl[(wn + ni*16 + li)*64 + rd0]);
      bfr[ni][1] = *reinterpret_cast<const bf16x8*>(&Bl[(wn + ni*16 + li)*64 + rd1]);
    }
    __builtin_amdgcn_s_setprio(1);
    #pragma unroll
    for (int mi = 0; mi < 4; ++mi)
      #pragma unroll
      for (int ni = 0; ni < 2; ++ni) {
        acc[mi][ni] = __builtin_amdgcn_mfma_f32_16x16x32_bf16(af[mi][0], bfr[ni][0], acc[mi][ni], 0, 0, 0);
        acc[mi][ni] = __builtin_amdgcn_mfma_f32_16x16x32_bf16(af[mi][1], bfr[ni][1], acc[mi][ni], 0, 0, 0);
      }
    __builtin_amdgcn_s_setprio(0);
    __syncthreads();
  }

  #pragma unroll
  for (int mi = 0; mi < 4; ++mi) {
    #pragma unroll
    for (int ni = 0; ni < 2; ++ni) {
      #pragma unroll
      for (int r = 0; r < 4; ++r) {
        const int grow = m0 + mi*16 + g*4 + r;
        const int gcol = n0 + wn + ni*16 + li;
        float v = acc[mi][ni][r];
        if constexpr (MODE == 1) {
          v += bias[grow];
          ((__hip_bfloat16*)C)[(size_t)grow*8192 + gcol] = __float2bfloat16(v);
        } else {
          v += bias[gcol];
          ((float*)C)[(size_t)grow*1024 + gcol] = v;
        }
      }
    }
  }
}

// merged QKV: 2048 blocks = 1024 QK (128x128) + 1024 Vt (64x128); XCD-bijective.
__global__ __launch_bounds__(256) void qkv_gemm(
    const __hip_bfloat16* __restrict__ xn,
    const __hip_bfloat16* __restrict__ Wqk,
    const __hip_bfloat16* __restrict__ Wvb,
    const float* __restrict__ bq, const float* __restrict__ bk,
    const float* __restrict__ bv,
    __hip_bfloat16* __restrict__ Qb, __hip_bfloat16* __restrict__ Kb,
    __hip_bfloat16* __restrict__ Vt)
{
  __shared__ __align__(16) __hip_bfloat16 Al[128*64];
  __shared__ __align__(16) __hip_bfloat16 Bl[128*64];
  const int lin = blockIdx.x;
  const int wg  = (lin & 7) * 256 + (lin >> 3);
  if (wg < 1024) {
    const int m0 = (wg >> 4) * 128, n0 = (wg & 15) * 128;
    gemm_body128(xn, Wqk, m0, n0, bq, bk, Qb, Kb, Al, Bl);
  } else {
    const int w2 = wg - 1024;
    const int m0 = (w2 >> 6) * 64, n0 = (w2 & 63) * 128;
    gemm_body_thin<1>(Wvb, xn, m0, n0, bv, Vt, Al, Bl);
  }
}

// output projection: 1024 blocks of 64x128 tiles (full-occupancy single pass)
__global__ __launch_bounds__(256) void out_gemm(
    const __hip_bfloat16* __restrict__ A,
    const __hip_bfloat16* __restrict__ B,
    const float* __restrict__ bias,
    float* __restrict__ C)
{
  __shared__ __align__(16) __hip_bfloat16 Al[64*64];
  __shared__ __align__(16) __hip_bfloat16 Bl[128*64];
  const int lin = blockIdx.x;
  const int wg  = (lin & 7) * 128 + (lin >> 3);
  const int m0 = (wg >> 3) * 64, n0 = (wg & 7) * 128;
  gemm_body_thin<2>(A, B, m0, n0, bias, C, Al, Bl);
}

// ---------------- Flash attention (unrolled x2: static buffers, ones-MFMA l) ----
// grid 1024 x 512 threads (8 waves x 16 q-rows, 32 waves/CU). Q pre-scaled by
// 0.125*log2(e); zero-max softmax p = v_exp_f32(s); in-register P; l via
// mfma(ones, aP). Unroll-by-2 makes all LDS addresses loop-invariant.
__global__ __launch_bounds__(512, 8) void attn_kernel(
    const __hip_bfloat16* __restrict__ Q,
    const __hip_bfloat16* __restrict__ K,
    const __hip_bfloat16* __restrict__ Vt,
    __hip_bfloat16* __restrict__ ctx)
{
  const int t = threadIdx.x, wave = t >> 6, lane = t & 63;
  const int li = lane & 15, g = lane >> 4;

  const int lin = blockIdx.x;
  const int wg  = (lin & 7) * 128 + (lin >> 3);
  const int bh  = wg >> 4, qt = wg & 15;
  const int b = bh >> 4, h = bh & 15;
  const int qbase = qt * 128 + wave * 16;

  __shared__ __align__(16) __hip_bfloat16 Klds[2][4096];
  __shared__ __align__(16) __hip_bfloat16 Vlds[2][4096];

  const bf16x8* Qv = reinterpret_cast<const bf16x8*>(Q + ((size_t)bh*2048 + qbase + li)*64 + g*8);
  const bf16x8 aQ0 = Qv[0], aQ1 = Qv[4];

  const short8 ones_s = { 0x3F80, 0x3F80, 0x3F80, 0x3F80, 0x3F80, 0x3F80, 0x3F80, 0x3F80 };
  const bf16x8 ones = __builtin_bit_cast(bf16x8, ones_s);

  f32x4 acc[4] = {};
  f32x4 acc_l = {};

  const __hip_bfloat16* Kbh = K + (size_t)bh*2048*64;
  const __hip_bfloat16* Vbh = Vt + (size_t)h*64*8192 + b*2048;

  const int row0 = t >> 3;
  const int scb_e = ((((t & 7) * 16) ^ ((row0 & 7) << 4)) >> 1);

  const int krd0 = (li*128 + ((g*16)      ^ ((li & 7) << 4))) >> 1;
  const int krd1 = (li*128 + ((g*16 + 64) ^ ((li & 7) << 4))) >> 1;

  // per-iteration compute on a fixed buffer pair (addresses loop-invariant)
  auto compute = [&](const __hip_bfloat16* Kc, const __hip_bfloat16* Vc) {
    f32x4 s[4] = {};
    __builtin_amdgcn_s_setprio(1);
    #pragma unroll
    for (int nt = 0; nt < 4; ++nt) {
      const bf16x8 k0 = *reinterpret_cast<const bf16x8*>(&Kc[nt*1024 + krd0]);
      const bf16x8 k1 = *reinterpret_cast<const bf16x8*>(&Kc[nt*1024 + krd1]);
      s[nt] = __builtin_amdgcn_mfma_f32_16x16x32_bf16(k0, aQ0, s[nt], 0, 0, 0);
      s[nt] = __builtin_amdgcn_mfma_f32_16x16x32_bf16(k1, aQ1, s[nt], 0, 0, 0);
    }
    __builtin_amdgcn_s_setprio(0);

    #pragma unroll
    for (int nt = 0; nt < 4; ++nt)
      #pragma unroll
      for (int r = 0; r < 4; ++r)
        s[nt][r] = fast_exp2(s[nt][r]);

    union U8 { uint32_t w[4]; bf16x8 v; };
    bf16x8 aP0, aP1;
    {
      uint32_t c[4][2];
      #pragma unroll
      for (int nt = 0; nt < 4; ++nt) {
        c[nt][0] = cvtpk_bf16(s[nt][0], s[nt][1]);
        c[nt][1] = cvtpk_bf16(s[nt][2], s[nt][3]);
      }
      uint32_t x0 = c[0][0], y0 = c[1][0], x1 = c[0][1], y1 = c[1][1];
      plswap32(x0, y0); plswap32(x1, y1);
      plswap16(x0, y0); plswap16(x1, y1);
      U8 u0; u0.w[0] = x0; u0.w[1] = x1; u0.w[2] = y0; u0.w[3] = y1;
      aP0 = u0.v;
      uint32_t x2 = c[2][0], y2 = c[3][0], x3 = c[2][1], y3 = c[3][1];
      plswap32(x2, y2); plswap32(x3, y3);
      plswap16(x2, y2); plswap16(x3, y3);
      U8 u1; u1.w[0] = x2; u1.w[1] = x3; u1.w[2] = y2; u1.w[3] = y3;
      aP1 = u1.v;
    }

    __builtin_amdgcn_s_setprio(1);
    #pragma unroll
    for (int dt = 0; dt < 4; ++dt) {
      const bf16x8 v0 = *reinterpret_cast<const bf16x8*>(&Vc[dt*1024 + krd0]);
      const bf16x8 v1 = *reinterpret_cast<const bf16x8*>(&Vc[dt*1024 + krd1]);
      acc[dt] = __builtin_amdgcn_mfma_f32_16x16x32_bf16(v0, aP0, acc[dt], 0, 0, 0);
      acc[dt] = __builtin_amdgcn_mfma_f32_16x16x32_bf16(v1, aP1, acc[dt], 0, 0, 0);
    }
    acc_l = __builtin_amdgcn_mfma_f32_16x16x32_bf16(ones, aP0, acc_l, 0, 0, 0);
    acc_l = __builtin_amdgcn_mfma_f32_16x16x32_bf16(ones, aP1, acc_l, 0, 0, 0);
    __builtin_amdgcn_s_setprio(0);
  };

  // prologue: stage tiles 0 (buf0) and 1 (buf1)
  gload_lds16(Kbh + (size_t)row0*64 + scb_e,        &Klds[0][t*8]);
  gload_lds16(Vbh + (size_t)row0*8192 + scb_e,      &Vlds[0][t*8]);
  gload_lds16(Kbh + (size_t)(64+row0)*64 + scb_e,   &Klds[1][t*8]);
  gload_lds16(Vbh + (size_t)row0*8192 + 64 + scb_e, &Vlds[1][t*8]);
  asm volatile("s_waitcnt vmcnt(2)" ::: "memory");
  __builtin_amdgcn_sched_barrier(0);
  __builtin_amdgcn_s_barrier();

  const __hip_bfloat16* kSrc = Kbh + (size_t)(128 + row0)*64 + scb_e;
  const __hip_bfloat16* vSrc = Vbh + (size_t)row0*8192 + 128 + scb_e;

  for (int i = 0; i < 15; ++i) {
    // phase A: tile 2i (buf 0); stage tile 2i+2 -> buf 0
    compute(Klds[0], Vlds[0]);
    __builtin_amdgcn_s_barrier();
    gload_lds16(kSrc, &Klds[0][t*8]);
    gload_lds16(vSrc, &Vlds[0][t*8]);
    kSrc += 64*64; vSrc += 64;
    asm volatile("s_waitcnt vmcnt(2)" ::: "memory");
    __builtin_amdgcn_sched_barrier(0);
    __builtin_amdgcn_s_barrier();
    // phase B: tile 2i+1 (buf 1); stage tile 2i+3 -> buf 1
    compute(Klds[1], Vlds[1]);
    __builtin_amdgcn_s_barrier();
    gload_lds16(kSrc, &Klds[1][t*8]);
    gload_lds16(vSrc, &Vlds[1][t*8]);
    kSrc += 64*64; vSrc += 64;
    asm volatile("s_waitcnt vmcnt(2)" ::: "memory");
    __builtin_amdgcn_sched_barrier(0);
    __builtin_amdgcn_s_barrier();
  }
  // it = 30 (buf 0): no staging, drain tile-31 loads
  compute(Klds[0], Vlds[0]);
  __builtin_amdgcn_s_barrier();
  asm volatile("s_waitcnt vmcnt(0)" ::: "memory");
  __builtin_amdgcn_sched_barrier(0);
  __builtin_amdgcn_s_barrier();
  // it = 31 (buf 1)
  compute(Klds[1], Vlds[1]);

  // acc_l[0] holds the full row sum for q=li (MFMA-reduced)
  const float inv = 1.0f / acc_l[0];

  __hip_bfloat16* cp = ctx + ((size_t)(b*2048 + qbase))*1024 + h*64;
  #pragma unroll
  for (int dt = 0; dt < 4; ++dt) {
    ushort4 o;
    o.x = bf16_bits(acc[dt][0] * inv);
    o.y = bf16_bits(acc[dt][1] * inv);
    o.z = bf16_bits(acc[dt][2] * inv);
    o.w = bf16_bits(acc[dt][3] * inv);
    *reinterpret_cast<ushort4*>(&cp[(size_t)li*1024 + dt*16 + g*4]) = o;
  }
}

extern "C" void kernel_launch(void* const* d_in, const int* in_sizes, int n_in,
                              void* d_out, int out_size, void* d_ws, size_t ws_size,
                              hipStream_t stream)
{
  const float* x  = (const float*)d_in[0];
  const float* g  = (const float*)d_in[1];
  const float* be = (const float*)d_in[2];
  const float* Wq = (const float*)d_in[3];
  const float* bq = (const float*)d_in[4];
  const float* Wk = (const float*)d_in[5];
  const float* bk = (const float*)d_in[6];
  const float* Wv = (const float*)d_in[7];
  const float* bv = (const float*)d_in[8];
  const float* Wo = (const float*)d_in[9];
  const float* bo = (const float*)d_in[10];
  float* out = (float*)d_out;

  char* ws = (char*)d_ws;
  __hip_bfloat16* xn  = (__hip_bfloat16*)(ws);              // 16 MB
  __hip_bfloat16* Wqk = (__hip_bfloat16*)(ws + 16777216);   // 4 MB  [2048][1024]
  __hip_bfloat16* Wvb = (__hip_bfloat16*)(ws + 20971520);   // 2 MB
  __hip_bfloat16* Wob = (__hip_bfloat16*)(ws + 23068672);   // 2 MB
  __hip_bfloat16* Qb  = (__hip_bfloat16*)(ws + 25165824);   // 16 MB [bh][s][64]
  __hip_bfloat16* Kb  = (__hip_bfloat16*)(ws + 41943040);   // 16 MB
  __hip_bfloat16* Vt  = (__hip_bfloat16*)(ws + 58720256);   // 16 MB [1024][8192]
  __hip_bfloat16* ctx = (__hip_bfloat16*)(ws + 75497472);   // 16 MB [8192][1024]

  prep_kernel<<<12288, 256, 0, stream>>>(x, g, be, xn, Wq, Wk, Wv, Wo, Wqk, Wvb, Wob);
  qkv_gemm<<<2048, 256, 0, stream>>>(xn, Wqk, Wvb, bq, bk, bv, Qb, Kb, Vt);
  attn_kernel<<<1024, 512, 0, stream>>>(Qb, Kb, Vt, ctx);
  out_gemm<<<1024, 256, 0, stream>>>(ctx, Wob, bo, out);
}

// Round 17
// 196.525 us; speedup vs baseline: 1.1404x; 1.1404x over previous
//
#include <hip/hip_runtime.h>
#include <hip/hip_bf16.h>
#include <stdint.h>

typedef __bf16 bf16x8 __attribute__((ext_vector_type(8)));
typedef short short8 __attribute__((ext_vector_type(8)));
typedef float f32x4 __attribute__((ext_vector_type(4)));

#define LOG2E 1.44269504088896340736f

__device__ inline void gload_lds16(const void* g, void* l) {
  __builtin_amdgcn_global_load_lds((const __attribute__((address_space(1))) void*)g,
                                   (__attribute__((address_space(3))) void*)l, 16, 0, 0);
}

__device__ inline unsigned short bf16_bits(float f) {
  return __builtin_bit_cast(unsigned short, __float2bfloat16(f));
}

// raw v_exp_f32 (exp2f is a multi-instruction OCML call; scores are bounded)
__device__ inline float fast_exp2(float x) {
  return __builtin_amdgcn_exp2f(x);
}

// pack two f32 -> one u32 of 2 bf16 (low = first arg)
__device__ inline uint32_t cvtpk_bf16(float lo, float hi) {
  uint32_t d;
  asm("v_cvt_pk_bf16_f32 %0, %1, %2" : "=v"(d) : "v"(lo), "v"(hi));
  return d;
}
// gfx950 cross-lane row swaps
__device__ inline void plswap32(uint32_t& a, uint32_t& b) {
  asm("v_permlane32_swap_b32 %0, %1" : "+v"(a), "+v"(b));
}
__device__ inline void plswap16(uint32_t& a, uint32_t& b) {
  asm("v_permlane16_swap_b32 %0, %1" : "+v"(a), "+v"(b));
}

// ---------------- prep: LN (blocks 0..8191) + weight cvt (blocks 8192..12287) ----
__global__ __launch_bounds__(256) void prep_kernel(
    const float* __restrict__ x, const float* __restrict__ gamma,
    const float* __restrict__ beta, __hip_bfloat16* __restrict__ xn,
    const float* __restrict__ Wq, const float* __restrict__ Wk,
    const float* __restrict__ Wv, const float* __restrict__ Wo,
    __hip_bfloat16* __restrict__ Wqk, __hip_bfloat16* __restrict__ Wvb,
    __hip_bfloat16* __restrict__ Wob)
{
  const int t = threadIdx.x;
  if (blockIdx.x < 8192) {
    const int row = blockIdx.x;
    const float4 v = reinterpret_cast<const float4*>(x + (size_t)row * 1024)[t];
    float s = v.x + v.y + v.z + v.w;
    float q = v.x*v.x + v.y*v.y + v.z*v.z + v.w*v.w;
    #pragma unroll
    for (int off = 32; off >= 1; off >>= 1) {
      s += __shfl_xor(s, off);
      q += __shfl_xor(q, off);
    }
    __shared__ float ls[4], lq[4];
    const int wave = t >> 6, lane = t & 63;
    if (lane == 0) { ls[wave] = s; lq[wave] = q; }
    __syncthreads();
    s = ls[0] + ls[1] + ls[2] + ls[3];
    q = lq[0] + lq[1] + lq[2] + lq[3];
    const float mean = s * (1.0f/1024.0f);
    const float var  = q * (1.0f/1024.0f) - mean*mean;
    const float rstd = rsqrtf(var + 1e-6f);
    const float4 gm = reinterpret_cast<const float4*>(gamma)[t];
    const float4 bt = reinterpret_cast<const float4*>(beta)[t];
    ushort4 o;
    o.x = bf16_bits((v.x - mean)*rstd*gm.x + bt.x);
    o.y = bf16_bits((v.y - mean)*rstd*gm.y + bt.y);
    o.z = bf16_bits((v.z - mean)*rstd*gm.z + bt.z);
    o.w = bf16_bits((v.w - mean)*rstd*gm.w + bt.w);
    reinterpret_cast<ushort4*>(xn + (size_t)row*1024)[t] = o;
  } else {
    const int cb = blockIdx.x - 8192;        // 0..4095
    const int which = cb >> 10;              // 0..3
    const int i = (cb & 1023) * 256 + t;     // 0..1M-1
    const float* src;
    __hip_bfloat16* dst;
    if (which == 0)      { src = Wq; dst = Wqk; }
    else if (which == 1) { src = Wk; dst = Wqk + 1024*1024; }
    else if (which == 2) { src = Wv; dst = Wvb; }
    else                 { src = Wo; dst = Wob; }
    const float4 v = reinterpret_cast<const float4*>(src)[i];
    ushort4 o;
    o.x = bf16_bits(v.x); o.y = bf16_bits(v.y);
    o.z = bf16_bits(v.z); o.w = bf16_bits(v.w);
    reinterpret_cast<ushort4*>(dst)[i] = o;
  }
}

// ---------------- NT-GEMM core: 128x128 tile, BK=64, XOR-swizzled LDS ----------
// (R14-proven; MODE 0: Q/K; MODE 1: Vt; MODE 2: out f32)
template<int MODE>
__device__ __forceinline__ void gemm_body(
    const __hip_bfloat16* __restrict__ A,
    const __hip_bfloat16* __restrict__ B,
    int m0, int n0,
    const float* __restrict__ bias0,
    const float* __restrict__ bias1,
    void* __restrict__ C0,
    void* __restrict__ C1,
    __hip_bfloat16* Al, __hip_bfloat16* Bl)
{
  constexpr int K = 1024;
  const int t = threadIdx.x;
  const int wave = t >> 6, lane = t & 63;
  const int li = lane & 15, g = lane >> 4;
  const int wm = (wave >> 1) * 64, wn = (wave & 1) * 64;

  const int srow = t >> 3;
  const int scb_e = ((((t & 7) * 16) ^ ((srow & 7) << 4)) >> 1);
  const __hip_bfloat16* ga = A + (size_t)(m0 + srow) * K + scb_e;
  const __hip_bfloat16* gb = B + (size_t)(n0 + srow) * K + scb_e;

  const int swz = (li & 7) << 4;
  const int rd0 = (((g*16)      ^ swz) >> 1);
  const int rd1 = (((g*16 + 64) ^ swz) >> 1);

  f32x4 acc[4][4] = {};

  for (int kt = 0; kt < K; kt += 64) {
    #pragma unroll
    for (int i = 0; i < 4; ++i) {
      gload_lds16(ga + (size_t)(i*32)*K + kt, Al + i*2048 + t*8);
      gload_lds16(gb + (size_t)(i*32)*K + kt, Bl + i*2048 + t*8);
    }
    __syncthreads();
    bf16x8 af[4][2], bfr[4][2];
    #pragma unroll
    for (int mi = 0; mi < 4; ++mi) {
      af[mi][0] = *reinterpret_cast<const bf16x8*>(&Al[(wm + mi*16 + li)*64 + rd0]);
      af[mi][1] = *reinterpret_cast<const bf16x8*>(&Al[(wm + mi*16 + li)*64 + rd1]);
    }
    #pragma unroll
    for (int ni = 0; ni < 4; ++ni) {
      bfr[ni][0] = *reinterpret_cast<const bf16x8*>(&Bl[(wn + ni*16 + li)*64 + rd0]);
      bfr[ni][1] = *reinterpret_cast<const bf16x8*>(&Bl[(wn + ni*16 + li)*64 + rd1]);
    }
    __builtin_amdgcn_s_setprio(1);
    #pragma unroll
    for (int mi = 0; mi < 4; ++mi)
      #pragma unroll
      for (int ni = 0; ni < 4; ++ni) {
        acc[mi][ni] = __builtin_amdgcn_mfma_f32_16x16x32_bf16(af[mi][0], bfr[ni][0], acc[mi][ni], 0, 0, 0);
        acc[mi][ni] = __builtin_amdgcn_mfma_f32_16x16x32_bf16(af[mi][1], bfr[ni][1], acc[mi][ni], 0, 0, 0);
      }
    __builtin_amdgcn_s_setprio(0);
    __syncthreads();
  }

  #pragma unroll
  for (int mi = 0; mi < 4; ++mi) {
    #pragma unroll
    for (int ni = 0; ni < 4; ++ni) {
      #pragma unroll
      for (int r = 0; r < 4; ++r) {
        const int grow = m0 + wm + mi*16 + g*4 + r;
        const int gcol = n0 + wn + ni*16 + li;
        float v = acc[mi][ni][r];
        if constexpr (MODE == 0) {
          const int b = grow >> 11, ss = grow & 2047;
          if (gcol < 1024) {
            // fold 1/sqrt(hd) AND log2(e) into Q so attn uses exp2 directly
            v = (v + bias0[gcol]) * (0.125f * LOG2E);
            const int h = gcol >> 6, d = gcol & 63;
            ((__hip_bfloat16*)C0)[(((size_t)(b*16 + h))*2048 + ss)*64 + d] = __float2bfloat16(v);
          } else {
            const int c2 = gcol - 1024;
            v = v + bias1[c2];
            const int h = c2 >> 6, d = c2 & 63;
            ((__hip_bfloat16*)C1)[(((size_t)(b*16 + h))*2048 + ss)*64 + d] = __float2bfloat16(v);
          }
        } else if constexpr (MODE == 1) {
          v += bias0[grow];
          ((__hip_bfloat16*)C0)[(size_t)grow*8192 + gcol] = __float2bfloat16(v);
        } else {
          v += bias0[gcol];
          ((float*)C0)[(size_t)grow*1024 + gcol] = v;
        }
      }
    }
  }
}

// merged QKV: 1536 blocks (XCD-bijective). wg<1024 -> [Q;K] tiles; else Vt tiles.
__global__ __launch_bounds__(256) void qkv_gemm(
    const __hip_bfloat16* __restrict__ xn,
    const __hip_bfloat16* __restrict__ Wqk,
    const __hip_bfloat16* __restrict__ Wvb,
    const float* __restrict__ bq, const float* __restrict__ bk,
    const float* __restrict__ bv,
    __hip_bfloat16* __restrict__ Qb, __hip_bfloat16* __restrict__ Kb,
    __hip_bfloat16* __restrict__ Vt)
{
  __shared__ __align__(16) __hip_bfloat16 Al[128*64];
  __shared__ __align__(16) __hip_bfloat16 Bl[128*64];
  const int lin = blockIdx.x;
  const int wg  = (lin & 7) * 192 + (lin >> 3);
  if (wg < 1024) {
    const int m0 = (wg >> 4) * 128, n0 = (wg & 15) * 128;
    gemm_body<0>(xn, Wqk, m0, n0, bq, bk, Qb, Kb, Al, Bl);
  } else {
    const int w2 = wg - 1024;
    const int m0 = (w2 & 7) * 128, n0 = (w2 >> 3) * 128;
    gemm_body<1>(Wvb, xn, m0, n0, bv, nullptr, Vt, nullptr, Al, Bl);
  }
}

// output projection: 512 blocks (XCD-chunked), 128x128 tiles
__global__ __launch_bounds__(256) void out_gemm(
    const __hip_bfloat16* __restrict__ A,
    const __hip_bfloat16* __restrict__ B,
    const float* __restrict__ bias,
    float* __restrict__ C)
{
  __shared__ __align__(16) __hip_bfloat16 Al[128*64];
  __shared__ __align__(16) __hip_bfloat16 Bl[128*64];
  const int lin = blockIdx.x;
  const int wg  = (lin & 7) * 64 + (lin >> 3);   // 512 blocks, 64 per XCD
  const int m0 = (wg >> 3) * 128, n0 = (wg & 7) * 128;
  gemm_body<2>(A, B, m0, n0, bias, nullptr, C, nullptr, Al, Bl);
}

// ---------------- Flash attention (unrolled x2: static buffers, ones-MFMA l) ----
// grid 1024 x 512 threads (8 waves x 16 q-rows, 32 waves/CU). Q pre-scaled by
// 0.125*log2(e); zero-max softmax p = v_exp_f32(s); in-register P; l via
// mfma(ones, aP). Unroll-by-2 makes all LDS addresses loop-invariant.
__global__ __launch_bounds__(512, 8) void attn_kernel(
    const __hip_bfloat16* __restrict__ Q,
    const __hip_bfloat16* __restrict__ K,
    const __hip_bfloat16* __restrict__ Vt,
    __hip_bfloat16* __restrict__ ctx)
{
  const int t = threadIdx.x, wave = t >> 6, lane = t & 63;
  const int li = lane & 15, g = lane >> 4;

  const int lin = blockIdx.x;
  const int wg  = (lin & 7) * 128 + (lin >> 3);
  const int bh  = wg >> 4, qt = wg & 15;
  const int b = bh >> 4, h = bh & 15;
  const int qbase = qt * 128 + wave * 16;

  __shared__ __align__(16) __hip_bfloat16 Klds[2][4096];
  __shared__ __align__(16) __hip_bfloat16 Vlds[2][4096];

  const bf16x8* Qv = reinterpret_cast<const bf16x8*>(Q + ((size_t)bh*2048 + qbase + li)*64 + g*8);
  const bf16x8 aQ0 = Qv[0], aQ1 = Qv[4];

  const short8 ones_s = { 0x3F80, 0x3F80, 0x3F80, 0x3F80, 0x3F80, 0x3F80, 0x3F80, 0x3F80 };
  const bf16x8 ones = __builtin_bit_cast(bf16x8, ones_s);

  f32x4 acc[4] = {};
  f32x4 acc_l = {};

  const __hip_bfloat16* Kbh = K + (size_t)bh*2048*64;
  const __hip_bfloat16* Vbh = Vt + (size_t)h*64*8192 + b*2048;

  const int row0 = t >> 3;
  const int scb_e = ((((t & 7) * 16) ^ ((row0 & 7) << 4)) >> 1);

  const int krd0 = (li*128 + ((g*16)      ^ ((li & 7) << 4))) >> 1;
  const int krd1 = (li*128 + ((g*16 + 64) ^ ((li & 7) << 4))) >> 1;

  // per-iteration compute on a fixed buffer pair (addresses loop-invariant)
  auto compute = [&](const __hip_bfloat16* Kc, const __hip_bfloat16* Vc) {
    f32x4 s[4] = {};
    __builtin_amdgcn_s_setprio(1);
    #pragma unroll
    for (int nt = 0; nt < 4; ++nt) {
      const bf16x8 k0 = *reinterpret_cast<const bf16x8*>(&Kc[nt*1024 + krd0]);
      const bf16x8 k1 = *reinterpret_cast<const bf16x8*>(&Kc[nt*1024 + krd1]);
      s[nt] = __builtin_amdgcn_mfma_f32_16x16x32_bf16(k0, aQ0, s[nt], 0, 0, 0);
      s[nt] = __builtin_amdgcn_mfma_f32_16x16x32_bf16(k1, aQ1, s[nt], 0, 0, 0);
    }
    __builtin_amdgcn_s_setprio(0);

    #pragma unroll
    for (int nt = 0; nt < 4; ++nt)
      #pragma unroll
      for (int r = 0; r < 4; ++r)
        s[nt][r] = fast_exp2(s[nt][r]);

    union U8 { uint32_t w[4]; bf16x8 v; };
    bf16x8 aP0, aP1;
    {
      uint32_t c[4][2];
      #pragma unroll
      for (int nt = 0; nt < 4; ++nt) {
        c[nt][0] = cvtpk_bf16(s[nt][0], s[nt][1]);
        c[nt][1] = cvtpk_bf16(s[nt][2], s[nt][3]);
      }
      uint32_t x0 = c[0][0], y0 = c[1][0], x1 = c[0][1], y1 = c[1][1];
      plswap32(x0, y0); plswap32(x1, y1);
      plswap16(x0, y0); plswap16(x1, y1);
      U8 u0; u0.w[0] = x0; u0.w[1] = x1; u0.w[2] = y0; u0.w[3] = y1;
      aP0 = u0.v;
      uint32_t x2 = c[2][0], y2 = c[3][0], x3 = c[2][1], y3 = c[3][1];
      plswap32(x2, y2); plswap32(x3, y3);
      plswap16(x2, y2); plswap16(x3, y3);
      U8 u1; u1.w[0] = x2; u1.w[1] = x3; u1.w[2] = y2; u1.w[3] = y3;
      aP1 = u1.v;
    }

    __builtin_amdgcn_s_setprio(1);
    #pragma unroll
    for (int dt = 0; dt < 4; ++dt) {
      const bf16x8 v0 = *reinterpret_cast<const bf16x8*>(&Vc[dt*1024 + krd0]);
      const bf16x8 v1 = *reinterpret_cast<const bf16x8*>(&Vc[dt*1024 + krd1]);
      acc[dt] = __builtin_amdgcn_mfma_f32_16x16x32_bf16(v0, aP0, acc[dt], 0, 0, 0);
      acc[dt] = __builtin_amdgcn_mfma_f32_16x16x32_bf16(v1, aP1, acc[dt], 0, 0, 0);
    }
    acc_l = __builtin_amdgcn_mfma_f32_16x16x32_bf16(ones, aP0, acc_l, 0, 0, 0);
    acc_l = __builtin_amdgcn_mfma_f32_16x16x32_bf16(ones, aP1, acc_l, 0, 0, 0);
    __builtin_amdgcn_s_setprio(0);
  };

  // prologue: stage tiles 0 (buf0) and 1 (buf1)
  gload_lds16(Kbh + (size_t)row0*64 + scb_e,        &Klds[0][t*8]);
  gload_lds16(Vbh + (size_t)row0*8192 + scb_e,      &Vlds[0][t*8]);
  gload_lds16(Kbh + (size_t)(64+row0)*64 + scb_e,   &Klds[1][t*8]);
  gload_lds16(Vbh + (size_t)row0*8192 + 64 + scb_e, &Vlds[1][t*8]);
  asm volatile("s_waitcnt vmcnt(2)" ::: "memory");
  __builtin_amdgcn_sched_barrier(0);
  __builtin_amdgcn_s_barrier();

  const __hip_bfloat16* kSrc = Kbh + (size_t)(128 + row0)*64 + scb_e;
  const __hip_bfloat16* vSrc = Vbh + (size_t)row0*8192 + 128 + scb_e;

  for (int i = 0; i < 15; ++i) {
    // phase A: tile 2i (buf 0); stage tile 2i+2 -> buf 0
    compute(Klds[0], Vlds[0]);
    __builtin_amdgcn_s_barrier();
    gload_lds16(kSrc, &Klds[0][t*8]);
    gload_lds16(vSrc, &Vlds[0][t*8]);
    kSrc += 64*64; vSrc += 64;
    asm volatile("s_waitcnt vmcnt(2)" ::: "memory");
    __builtin_amdgcn_sched_barrier(0);
    __builtin_amdgcn_s_barrier();
    // phase B: tile 2i+1 (buf 1); stage tile 2i+3 -> buf 1
    compute(Klds[1], Vlds[1]);
    __builtin_amdgcn_s_barrier();
    gload_lds16(kSrc, &Klds[1][t*8]);
    gload_lds16(vSrc, &Vlds[1][t*8]);
    kSrc += 64*64; vSrc += 64;
    asm volatile("s_waitcnt vmcnt(2)" ::: "memory");
    __builtin_amdgcn_sched_barrier(0);
    __builtin_amdgcn_s_barrier();
  }
  // it = 30 (buf 0): no staging, drain tile-31 loads
  compute(Klds[0], Vlds[0]);
  __builtin_amdgcn_s_barrier();
  asm volatile("s_waitcnt vmcnt(0)" ::: "memory");
  __builtin_amdgcn_sched_barrier(0);
  __builtin_amdgcn_s_barrier();
  // it = 31 (buf 1)
  compute(Klds[1], Vlds[1]);

  // acc_l[0] holds the full row sum for q=li (MFMA-reduced)
  const float inv = 1.0f / acc_l[0];

  __hip_bfloat16* cp = ctx + ((size_t)(b*2048 + qbase))*1024 + h*64;
  #pragma unroll
  for (int dt = 0; dt < 4; ++dt) {
    ushort4 o;
    o.x = bf16_bits(acc[dt][0] * inv);
    o.y = bf16_bits(acc[dt][1] * inv);
    o.z = bf16_bits(acc[dt][2] * inv);
    o.w = bf16_bits(acc[dt][3] * inv);
    *reinterpret_cast<ushort4*>(&cp[(size_t)li*1024 + dt*16 + g*4]) = o;
  }
}

extern "C" void kernel_launch(void* const* d_in, const int* in_sizes, int n_in,
                              void* d_out, int out_size, void* d_ws, size_t ws_size,
                              hipStream_t stream)
{
  const float* x  = (const float*)d_in[0];
  const float* g  = (const float*)d_in[1];
  const float* be = (const float*)d_in[2];
  const float* Wq = (const float*)d_in[3];
  const float* bq = (const float*)d_in[4];
  const float* Wk = (const float*)d_in[5];
  const float* bk = (const float*)d_in[6];
  const float* Wv = (const float*)d_in[7];
  const float* bv = (const float*)d_in[8];
  const float* Wo = (const float*)d_in[9];
  const float* bo = (const float*)d_in[10];
  float* out = (float*)d_out;

  char* ws = (char*)d_ws;
  __hip_bfloat16* xn  = (__hip_bfloat16*)(ws);              // 16 MB
  __hip_bfloat16* Wqk = (__hip_bfloat16*)(ws + 16777216);   // 4 MB  [2048][1024]
  __hip_bfloat16* Wvb = (__hip_bfloat16*)(ws + 20971520);   // 2 MB
  __hip_bfloat16* Wob = (__hip_bfloat16*)(ws + 23068672);   // 2 MB
  __hip_bfloat16* Qb  = (__hip_bfloat16*)(ws + 25165824);   // 16 MB [bh][s][64]
  __hip_bfloat16* Kb  = (__hip_bfloat16*)(ws + 41943040);   // 16 MB
  __hip_bfloat16* Vt  = (__hip_bfloat16*)(ws + 58720256);   // 16 MB [1024][8192]
  __hip_bfloat16* ctx = (__hip_bfloat16*)(ws + 75497472);   // 16 MB [8192][1024]

  prep_kernel<<<12288, 256, 0, stream>>>(x, g, be, xn, Wq, Wk, Wv, Wo, Wqk, Wvb, Wob);
  qkv_gemm<<<1536, 256, 0, stream>>>(xn, Wqk, Wvb, bq, bk, bv, Qb, Kb, Vt);
  attn_kernel<<<1024, 512, 0, stream>>>(Qb, Kb, Vt, ctx);
  out_gemm<<<512, 256, 0, stream>>>(ctx, Wob, bo, out);
}

// Round 18
// 188.718 us; speedup vs baseline: 1.1876x; 1.0414x over previous
//
#include <hip/hip_runtime.h>
#include <hip/hip_bf16.h>
#include <stdint.h>

typedef __bf16 bf16x8 __attribute__((ext_vector_type(8)));
typedef short short8 __attribute__((ext_vector_type(8)));
typedef float f32x4 __attribute__((ext_vector_type(4)));

#define LOG2E 1.44269504088896340736f

__device__ inline void gload_lds16(const void* g, void* l) {
  __builtin_amdgcn_global_load_lds((const __attribute__((address_space(1))) void*)g,
                                   (__attribute__((address_space(3))) void*)l, 16, 0, 0);
}

__device__ inline unsigned short bf16_bits(float f) {
  return __builtin_bit_cast(unsigned short, __float2bfloat16(f));
}

// raw v_exp_f32 (exp2f is a multi-instruction OCML call; scores are bounded)
__device__ inline float fast_exp2(float x) {
  return __builtin_amdgcn_exp2f(x);
}

// pack two f32 -> one u32 of 2 bf16 (low = first arg)
__device__ inline uint32_t cvtpk_bf16(float lo, float hi) {
  uint32_t d;
  asm("v_cvt_pk_bf16_f32 %0, %1, %2" : "=v"(d) : "v"(lo), "v"(hi));
  return d;
}
// gfx950 cross-lane row swaps
__device__ inline void plswap32(uint32_t& a, uint32_t& b) {
  asm("v_permlane32_swap_b32 %0, %1" : "+v"(a), "+v"(b));
}
__device__ inline void plswap16(uint32_t& a, uint32_t& b) {
  asm("v_permlane16_swap_b32 %0, %1" : "+v"(a), "+v"(b));
}

// ---------------- prep: LN (blocks 0..8191) + weight cvt (blocks 8192..12287) ----
__global__ __launch_bounds__(256) void prep_kernel(
    const float* __restrict__ x, const float* __restrict__ gamma,
    const float* __restrict__ beta, __hip_bfloat16* __restrict__ xn,
    const float* __restrict__ Wq, const float* __restrict__ Wk,
    const float* __restrict__ Wv, const float* __restrict__ Wo,
    __hip_bfloat16* __restrict__ Wqk, __hip_bfloat16* __restrict__ Wvb,
    __hip_bfloat16* __restrict__ Wob)
{
  const int t = threadIdx.x;
  if (blockIdx.x < 8192) {
    const int row = blockIdx.x;
    const float4 v = reinterpret_cast<const float4*>(x + (size_t)row * 1024)[t];
    float s = v.x + v.y + v.z + v.w;
    float q = v.x*v.x + v.y*v.y + v.z*v.z + v.w*v.w;
    #pragma unroll
    for (int off = 32; off >= 1; off >>= 1) {
      s += __shfl_xor(s, off);
      q += __shfl_xor(q, off);
    }
    __shared__ float ls[4], lq[4];
    const int wave = t >> 6, lane = t & 63;
    if (lane == 0) { ls[wave] = s; lq[wave] = q; }
    __syncthreads();
    s = ls[0] + ls[1] + ls[2] + ls[3];
    q = lq[0] + lq[1] + lq[2] + lq[3];
    const float mean = s * (1.0f/1024.0f);
    const float var  = q * (1.0f/1024.0f) - mean*mean;
    const float rstd = rsqrtf(var + 1e-6f);
    const float4 gm = reinterpret_cast<const float4*>(gamma)[t];
    const float4 bt = reinterpret_cast<const float4*>(beta)[t];
    ushort4 o;
    o.x = bf16_bits((v.x - mean)*rstd*gm.x + bt.x);
    o.y = bf16_bits((v.y - mean)*rstd*gm.y + bt.y);
    o.z = bf16_bits((v.z - mean)*rstd*gm.z + bt.z);
    o.w = bf16_bits((v.w - mean)*rstd*gm.w + bt.w);
    reinterpret_cast<ushort4*>(xn + (size_t)row*1024)[t] = o;
  } else {
    const int cb = blockIdx.x - 8192;        // 0..4095
    const int which = cb >> 10;              // 0..3
    const int i = (cb & 1023) * 256 + t;     // 0..1M-1
    const float* src;
    __hip_bfloat16* dst;
    if (which == 0)      { src = Wq; dst = Wqk; }
    else if (which == 1) { src = Wk; dst = Wqk + 1024*1024; }
    else if (which == 2) { src = Wv; dst = Wvb; }
    else                 { src = Wo; dst = Wob; }
    const float4 v = reinterpret_cast<const float4*>(src)[i];
    ushort4 o;
    o.x = bf16_bits(v.x); o.y = bf16_bits(v.y);
    o.z = bf16_bits(v.z); o.w = bf16_bits(v.w);
    reinterpret_cast<ushort4*>(dst)[i] = o;
  }
}

// ---------------- NT-GEMM core: 128x128 tile, BK=64, XOR-swizzled LDS ----------
template<int MODE>
__device__ __forceinline__ void gemm_body(
    const __hip_bfloat16* __restrict__ A,
    const __hip_bfloat16* __restrict__ B,
    int m0, int n0,
    const float* __restrict__ bias0,
    const float* __restrict__ bias1,
    void* __restrict__ C0,
    void* __restrict__ C1,
    __hip_bfloat16* Al, __hip_bfloat16* Bl)
{
  constexpr int K = 1024;
  const int t = threadIdx.x;
  const int wave = t >> 6, lane = t & 63;
  const int li = lane & 15, g = lane >> 4;
  const int wm = (wave >> 1) * 64, wn = (wave & 1) * 64;

  const int srow = t >> 3;                  // 0..31
  const int scb_e = ((((t & 7) * 16) ^ ((srow & 7) << 4)) >> 1);
  const __hip_bfloat16* ga = A + (size_t)(m0 + srow) * K + scb_e;
  const __hip_bfloat16* gb = B + (size_t)(n0 + srow) * K + scb_e;

  const int swz = (li & 7) << 4;
  const int rd0 = (((g*16)      ^ swz) >> 1);
  const int rd1 = (((g*16 + 64) ^ swz) >> 1);

  f32x4 acc[4][4] = {};

  for (int kt = 0; kt < K; kt += 64) {
    #pragma unroll
    for (int i = 0; i < 4; ++i) {
      gload_lds16(ga + (size_t)(i*32)*K + kt, Al + i*2048 + t*8);
      gload_lds16(gb + (size_t)(i*32)*K + kt, Bl + i*2048 + t*8);
    }
    __syncthreads();
    bf16x8 af[4][2], bfr[4][2];
    #pragma unroll
    for (int mi = 0; mi < 4; ++mi) {
      af[mi][0] = *reinterpret_cast<const bf16x8*>(&Al[(wm + mi*16 + li)*64 + rd0]);
      af[mi][1] = *reinterpret_cast<const bf16x8*>(&Al[(wm + mi*16 + li)*64 + rd1]);
    }
    #pragma unroll
    for (int ni = 0; ni < 4; ++ni) {
      bfr[ni][0] = *reinterpret_cast<const bf16x8*>(&Bl[(wn + ni*16 + li)*64 + rd0]);
      bfr[ni][1] = *reinterpret_cast<const bf16x8*>(&Bl[(wn + ni*16 + li)*64 + rd1]);
    }
    __builtin_amdgcn_s_setprio(1);
    #pragma unroll
    for (int mi = 0; mi < 4; ++mi)
      #pragma unroll
      for (int ni = 0; ni < 4; ++ni) {
        acc[mi][ni] = __builtin_amdgcn_mfma_f32_16x16x32_bf16(af[mi][0], bfr[ni][0], acc[mi][ni], 0, 0, 0);
        acc[mi][ni] = __builtin_amdgcn_mfma_f32_16x16x32_bf16(af[mi][1], bfr[ni][1], acc[mi][ni], 0, 0, 0);
      }
    __builtin_amdgcn_s_setprio(0);
    __syncthreads();
  }

  #pragma unroll
  for (int mi = 0; mi < 4; ++mi) {
    #pragma unroll
    for (int ni = 0; ni < 4; ++ni) {
      #pragma unroll
      for (int r = 0; r < 4; ++r) {
        const int grow = m0 + wm + mi*16 + g*4 + r;
        const int gcol = n0 + wn + ni*16 + li;
        float v = acc[mi][ni][r];
        if constexpr (MODE == 0) {
          const int b = grow >> 11, ss = grow & 2047;
          if (gcol < 1024) {
            // fold 1/sqrt(hd) AND log2(e) into Q so attn uses exp2 directly
            v = (v + bias0[gcol]) * (0.125f * LOG2E);
            const int h = gcol >> 6, d = gcol & 63;
            ((__hip_bfloat16*)C0)[(((size_t)(b*16 + h))*2048 + ss)*64 + d] = __float2bfloat16(v);
          } else {
            const int c2 = gcol - 1024;
            v = v + bias1[c2];
            const int h = c2 >> 6, d = c2 & 63;
            ((__hip_bfloat16*)C1)[(((size_t)(b*16 + h))*2048 + ss)*64 + d] = __float2bfloat16(v);
          }
        } else if constexpr (MODE == 1) {
          v += bias0[grow];
          ((__hip_bfloat16*)C0)[(size_t)grow*8192 + gcol] = __float2bfloat16(v);
        } else {
          v += bias0[gcol];
          ((float*)C0)[(size_t)grow*1024 + gcol] = v;
        }
      }
    }
  }
}

// merged QKV: 1536 blocks (XCD-bijective). wg<1024 -> [Q;K] tiles; else Vt tiles.
__global__ __launch_bounds__(256) void qkv_gemm(
    const __hip_bfloat16* __restrict__ xn,
    const __hip_bfloat16* __restrict__ Wqk,
    const __hip_bfloat16* __restrict__ Wvb,
    const float* __restrict__ bq, const float* __restrict__ bk,
    const float* __restrict__ bv,
    __hip_bfloat16* __restrict__ Qb, __hip_bfloat16* __restrict__ Kb,
    __hip_bfloat16* __restrict__ Vt)
{
  __shared__ __align__(16) __hip_bfloat16 Al[128*64];
  __shared__ __align__(16) __hip_bfloat16 Bl[128*64];
  const int lin = blockIdx.x;
  const int wg  = (lin & 7) * 192 + (lin >> 3);
  if (wg < 1024) {
    const int m0 = (wg >> 4) * 128, n0 = (wg & 15) * 128;
    gemm_body<0>(xn, Wqk, m0, n0, bq, bk, Qb, Kb, Al, Bl);
  } else {
    const int w2 = wg - 1024;
    const int m0 = (w2 & 7) * 128, n0 = (w2 >> 3) * 128;
    gemm_body<1>(Wvb, xn, m0, n0, bv, nullptr, Vt, nullptr, Al, Bl);
  }
}

// output projection: 512 blocks (XCD-chunked), 128x128 tiles
__global__ __launch_bounds__(256) void out_gemm(
    const __hip_bfloat16* __restrict__ A,
    const __hip_bfloat16* __restrict__ B,
    const float* __restrict__ bias,
    float* __restrict__ C)
{
  __shared__ __align__(16) __hip_bfloat16 Al[128*64];
  __shared__ __align__(16) __hip_bfloat16 Bl[128*64];
  const int lin = blockIdx.x;
  const int wg  = (lin & 7) * 64 + (lin >> 3);   // 512 blocks, 64 per XCD
  const int m0 = (wg >> 3) * 128, n0 = (wg & 7) * 128;
  gemm_body<2>(A, B, m0, n0, bias, nullptr, C, nullptr, Al, Bl);
}

// ---------------- Flash attention (8 waves x 16 q-rows, ones-MFMA l-sum) --------
// grid 1024 blocks x 512 threads; K/V staged once per block, T4 counted-vmcnt
// pipeline (rolled loop: keeps the 16 blocks sharing each bh in lockstep for
// L2 reuse -- the R17 unroll broke this and cost +12us). Q pre-scaled by
// 0.125*log2(e); zero-max softmax p = v_exp_f32(s). In-register P (cvt_pk +
// permlane). l = sum_k P[k][q] on the MFMA pipe via mfma(ones, aP).
__global__ __launch_bounds__(512, 8) void attn_kernel(
    const __hip_bfloat16* __restrict__ Q,
    const __hip_bfloat16* __restrict__ K,
    const __hip_bfloat16* __restrict__ Vt,
    __hip_bfloat16* __restrict__ ctx)
{
  const int t = threadIdx.x, wave = t >> 6, lane = t & 63;
  const int li = lane & 15, g = lane >> 4;

  const int lin = blockIdx.x;
  const int wg  = (lin & 7) * 128 + (lin >> 3);
  const int bh  = wg >> 4, qt = wg & 15;
  const int b = bh >> 4, h = bh & 15;
  const int qbase = qt * 128 + wave * 16;

  __shared__ __align__(16) __hip_bfloat16 Klds[2][4096];
  __shared__ __align__(16) __hip_bfloat16 Vlds[2][4096];

  const bf16x8* Qv = reinterpret_cast<const bf16x8*>(Q + ((size_t)bh*2048 + qbase + li)*64 + g*8);
  const bf16x8 aQ0 = Qv[0], aQ1 = Qv[4];

  const short8 ones_s = { 0x3F80, 0x3F80, 0x3F80, 0x3F80, 0x3F80, 0x3F80, 0x3F80, 0x3F80 };
  const bf16x8 ones = __builtin_bit_cast(bf16x8, ones_s);

  f32x4 acc[4] = {};
  f32x4 acc_l = {};   // l-sum accumulator (MFMA pipe)

  const __hip_bfloat16* Kbh = K + (size_t)bh*2048*64;
  const __hip_bfloat16* Vbh = Vt + (size_t)h*64*8192 + b*2048;

  const int row0 = t >> 3;
  const int scb_e = ((((t & 7) * 16) ^ ((row0 & 7) << 4)) >> 1);

  const int krd0 = (li*128 + ((g*16)      ^ ((li & 7) << 4))) >> 1;
  const int krd1 = (li*128 + ((g*16 + 64) ^ ((li & 7) << 4))) >> 1;

  gload_lds16(Kbh + (size_t)row0*64 + scb_e,        &Klds[0][t*8]);
  gload_lds16(Vbh + (size_t)row0*8192 + scb_e,      &Vlds[0][t*8]);
  gload_lds16(Kbh + (size_t)(64+row0)*64 + scb_e,   &Klds[1][t*8]);
  gload_lds16(Vbh + (size_t)row0*8192 + 64 + scb_e, &Vlds[1][t*8]);
  asm volatile("s_waitcnt vmcnt(2)" ::: "memory");
  __builtin_amdgcn_sched_barrier(0);
  __builtin_amdgcn_s_barrier();

  const __hip_bfloat16* kSrc = Kbh + (size_t)(128 + row0)*64 + scb_e;
  const __hip_bfloat16* vSrc = Vbh + (size_t)row0*8192 + 128 + scb_e;

  for (int it = 0; it < 32; ++it) {
    const int cur = it & 1;
    const __hip_bfloat16* Kc = Klds[cur];
    const __hip_bfloat16* Vc = Vlds[cur];

    f32x4 s[4] = {};
    __builtin_amdgcn_s_setprio(1);
    #pragma unroll
    for (int nt = 0; nt < 4; ++nt) {
      const bf16x8 k0 = *reinterpret_cast<const bf16x8*>(&Kc[nt*1024 + krd0]);
      const bf16x8 k1 = *reinterpret_cast<const bf16x8*>(&Kc[nt*1024 + krd1]);
      s[nt] = __builtin_amdgcn_mfma_f32_16x16x32_bf16(k0, aQ0, s[nt], 0, 0, 0);
      s[nt] = __builtin_amdgcn_mfma_f32_16x16x32_bf16(k1, aQ1, s[nt], 0, 0, 0);
    }
    __builtin_amdgcn_s_setprio(0);

    // zero-max softmax: p = v_exp_f32(s), in place (no sum -- MFMA does it)
    #pragma unroll
    for (int nt = 0; nt < 4; ++nt)
      #pragma unroll
      for (int r = 0; r < 4; ++r)
        s[nt][r] = fast_exp2(s[nt][r]);

    // in-register P redistribution (cvt_pk + permlane swaps)
    union U8 { uint32_t w[4]; bf16x8 v; };
    bf16x8 aP0, aP1;
    {
      uint32_t c[4][2];
      #pragma unroll
      for (int nt = 0; nt < 4; ++nt) {
        c[nt][0] = cvtpk_bf16(s[nt][0], s[nt][1]);
        c[nt][1] = cvtpk_bf16(s[nt][2], s[nt][3]);
      }
      uint32_t x0 = c[0][0], y0 = c[1][0], x1 = c[0][1], y1 = c[1][1];
      plswap32(x0, y0); plswap32(x1, y1);
      plswap16(x0, y0); plswap16(x1, y1);
      U8 u0; u0.w[0] = x0; u0.w[1] = x1; u0.w[2] = y0; u0.w[3] = y1;
      aP0 = u0.v;
      uint32_t x2 = c[2][0], y2 = c[3][0], x3 = c[2][1], y3 = c[3][1];
      plswap32(x2, y2); plswap32(x3, y3);
      plswap16(x2, y2); plswap16(x3, y3);
      U8 u1; u1.w[0] = x2; u1.w[1] = x3; u1.w[2] = y2; u1.w[3] = y3;
      aP1 = u1.v;
    }

    // PV swapped + l-sum on the MFMA pipe
    __builtin_amdgcn_s_setprio(1);
    #pragma unroll
    for (int dt = 0; dt < 4; ++dt) {
      const bf16x8 v0 = *reinterpret_cast<const bf16x8*>(&Vc[dt*1024 + krd0]);
      const bf16x8 v1 = *reinterpret_cast<const bf16x8*>(&Vc[dt*1024 + krd1]);
      acc[dt] = __builtin_amdgcn_mfma_f32_16x16x32_bf16(v0, aP0, acc[dt], 0, 0, 0);
      acc[dt] = __builtin_amdgcn_mfma_f32_16x16x32_bf16(v1, aP1, acc[dt], 0, 0, 0);
    }
    acc_l = __builtin_amdgcn_mfma_f32_16x16x32_bf16(ones, aP0, acc_l, 0, 0, 0);
    acc_l = __builtin_amdgcn_mfma_f32_16x16x32_bf16(ones, aP1, acc_l, 0, 0, 0);
    __builtin_amdgcn_s_setprio(0);

    if (it < 31) {
      __builtin_amdgcn_s_barrier();
      if (it < 30) {
        gload_lds16(kSrc, &Klds[cur][t*8]);
        gload_lds16(vSrc, &Vlds[cur][t*8]);
        kSrc += 64*64;
        vSrc += 64;
        asm volatile("s_waitcnt vmcnt(2)" ::: "memory");
      } else {
        asm volatile("s_waitcnt vmcnt(0)" ::: "memory");
      }
      __builtin_amdgcn_sched_barrier(0);
      __builtin_amdgcn_s_barrier();
    }
  }

  // acc_l[0] already holds the full row sum for q=li (MFMA-reduced)
  const float inv = 1.0f / acc_l[0];

  __hip_bfloat16* cp = ctx + ((size_t)(b*2048 + qbase))*1024 + h*64;
  #pragma unroll
  for (int dt = 0; dt < 4; ++dt) {
    ushort4 o;
    o.x = bf16_bits(acc[dt][0] * inv);
    o.y = bf16_bits(acc[dt][1] * inv);
    o.z = bf16_bits(acc[dt][2] * inv);
    o.w = bf16_bits(acc[dt][3] * inv);
    *reinterpret_cast<ushort4*>(&cp[(size_t)li*1024 + dt*16 + g*4]) = o;
  }
}

extern "C" void kernel_launch(void* const* d_in, const int* in_sizes, int n_in,
                              void* d_out, int out_size, void* d_ws, size_t ws_size,
                              hipStream_t stream)
{
  const float* x  = (const float*)d_in[0];
  const float* g  = (const float*)d_in[1];
  const float* be = (const float*)d_in[2];
  const float* Wq = (const float*)d_in[3];
  const float* bq = (const float*)d_in[4];
  const float* Wk = (const float*)d_in[5];
  const float* bk = (const float*)d_in[6];
  const float* Wv = (const float*)d_in[7];
  const float* bv = (const float*)d_in[8];
  const float* Wo = (const float*)d_in[9];
  const float* bo = (const float*)d_in[10];
  float* out = (float*)d_out;

  char* ws = (char*)d_ws;
  __hip_bfloat16* xn  = (__hip_bfloat16*)(ws);              // 16 MB
  __hip_bfloat16* Wqk = (__hip_bfloat16*)(ws + 16777216);   // 4 MB  [2048][1024]
  __hip_bfloat16* Wvb = (__hip_bfloat16*)(ws + 20971520);   // 2 MB
  __hip_bfloat16* Wob = (__hip_bfloat16*)(ws + 23068672);   // 2 MB
  __hip_bfloat16* Qb  = (__hip_bfloat16*)(ws + 25165824);   // 16 MB [bh][s][64]
  __hip_bfloat16* Kb  = (__hip_bfloat16*)(ws + 41943040);   // 16 MB
  __hip_bfloat16* Vt  = (__hip_bfloat16*)(ws + 58720256);   // 16 MB [1024][8192]
  __hip_bfloat16* ctx = (__hip_bfloat16*)(ws + 75497472);   // 16 MB [8192][1024]

  prep_kernel<<<12288, 256, 0, stream>>>(x, g, be, xn, Wq, Wk, Wv, Wo, Wqk, Wvb, Wob);
  qkv_gemm<<<1536, 256, 0, stream>>>(xn, Wqk, Wvb, bq, bk, bv, Qb, Kb, Vt);
  attn_kernel<<<1024, 512, 0, stream>>>(Qb, Kb, Vt, ctx);
  out_gemm<<<512, 256, 0, stream>>>(ctx, Wob, bo, out);
}